// Round 6
// baseline (138.576 us; speedup 1.0000x reference)
//
#include <hip/hip_runtime.h>

// Problem constants (from reference):
//   B=256, A=128, D=5, FA=256, FB=64, C=256, F = FA+FB = 320
// deg==5 (~96.2% of rows) -> output row exactly zero. Only deg<5 rows
// (~1250, ~98% deg==4) need feat(320) @ W[deg](320x256).
//
// Lessons so far:
//   R1: touching d_ws triggers a 256MiB re-poison fill (~41us/iter) -> never
//       use the workspace. Fixed floor = 2 poison fills ~83us + our kernel.
//   R2: concentrating needy work (512 blocks) serialized it: 69us.
//   R5: 4096-block version == 32768-block baseline (42.5 vs 43.7us) despite
//       4x fewer load round-trips in the matvec -> the invariant cost is the
//       33.5MB of in-kernel zero stores crawling at ~800GB/s (fillBuffer
//       does 6.5TB/s on this chip). Matvec is NOT the bottleneck.
//
// This version: give the bulk zero-fill to the runtime's tuned fill path.
//   op1: hipMemsetAsync(d_out, 0, 33.5MB)  -- ~5-6us at fill BW, capturable
//        (R1 proved memset captures; d_out is re-poisoned every iteration
//        anyway, so touching it adds no extra poison fill)
//   op2: ngh_needy -- round-5 kernel minus the zero-store phase (clean A/B):
//        4096 blocks x 8 rows; one 160B coalesced edge read; ~73% of blocks
//        exit immediately; needy rows do the 4-wave f-split float4 matvec
//        and overwrite their zeroed slot (stream order: memset -> kernel).

#define NB 256
#define NA 128
#define ND 5
#define NFA 256
#define NFB 64
#define NC 256
#define NF (NFA + NFB)     // 320
#define NROWS (NB * NA)    // 32768
#define RPB 8              // rows per block
#define NBLK (NROWS / RPB) // 4096 blocks

__global__ __launch_bounds__(256) void ngh_needy(
    const float* __restrict__ atoms,   // B*A*FA
    const float* __restrict__ bonds,   // B*A*D*FB (row slice = 320 contiguous)
    const int*   __restrict__ edges,   // B*A*D
    const float* __restrict__ W,       // D*F*C
    const float* __restrict__ bias,    // D*C
    float* __restrict__ out)           // B*A*C (pre-zeroed by memset)
{
    __shared__ alignas(16) float  feat[NF];      // 1.25 KB
    __shared__ alignas(16) float4 red[4][NC / 4];// 4 KB (per-wave partials)
    __shared__ int                eds[RPB * ND]; // 160 B

    const int t  = threadIdx.x;
    const int r0 = blockIdx.x * RPB;
    const int w  = t >> 6;             // wave id 0..3
    const int l  = t & 63;             // lane id

    // Stage this block's 40 edge ints with one coalesced load.
    if (t < RPB * ND) eds[t] = edges[r0 * ND + t];
    __syncthreads();

    // Degree scan -> needy bitmask (block-uniform: same LDS reads everywhere).
    unsigned needy = 0;
#pragma unroll
    for (int r = 0; r < RPB; ++r) {
        int dg = 0;
#pragma unroll
        for (int d = 0; d < ND; ++d) dg += (eds[r * ND + d] != -1) ? 1 : 0;
        needy |= (dg < ND) ? (1u << r) : 0u;
    }

    if (needy == 0u) return;           // ~73% of blocks: nothing to do

    // Every __syncthreads() below is executed by ALL threads (loop bounds
    // static, branch conditions block-uniform, barriers non-divergent).
    for (int r = 0; r < RPB; ++r) {
        if (!((needy >> r) & 1u)) continue;   // block-uniform
        const int row = r0 + r;

        int e[ND];
        int deg = 0;
#pragma unroll
        for (int d = 0; d < ND; ++d) {
            e[d] = eds[r * ND + d];
            deg += (e[d] != -1) ? 1 : 0;
        }

        // ---- feat = [summed_atom(256) | summed_bond(64)] in LDS ----
        {
            const int rb = row & ~(NA - 1);          // b*NA
            float v = atoms[(size_t)row * NFA + t];
#pragma unroll
            for (int d = 0; d < ND; ++d)
                if (e[d] != -1) v += atoms[(size_t)(rb + e[d]) * NFA + t];
            feat[t] = v;
            if (t < NFB) {
                const float* br = bonds + (size_t)row * (ND * NFB) + t;
                feat[NFA + t] = br[0] + br[NFB] + br[2 * NFB]
                              + br[3 * NFB] + br[4 * NFB];
            }
        }
        __syncthreads();               // feat ready

        // ---- matvec: wave w owns f in [80w, 80w+80); lane owns 4 channels.
        // float4 W loads: 64 lanes cover the 256-chan row (1KB/instr),
        // 80 load instrs per wave vs 320 scalar -> 4x fewer round-trips.
        const float* Wd = W + (size_t)deg * (NF * NC);
        float4 acc = make_float4(0.f, 0.f, 0.f, 0.f);
        const int fbase = w * (NF / 4);
#pragma unroll 2
        for (int fi = 0; fi < NF / 4; fi += 4) {
            const int f = fbase + fi;
            const float4 fv = *reinterpret_cast<const float4*>(&feat[f]);
            const float4 w0 = *reinterpret_cast<const float4*>(&Wd[(size_t)(f + 0) * NC + l * 4]);
            const float4 w1 = *reinterpret_cast<const float4*>(&Wd[(size_t)(f + 1) * NC + l * 4]);
            const float4 w2 = *reinterpret_cast<const float4*>(&Wd[(size_t)(f + 2) * NC + l * 4]);
            const float4 w3 = *reinterpret_cast<const float4*>(&Wd[(size_t)(f + 3) * NC + l * 4]);
            acc.x = fmaf(fv.x, w0.x, acc.x);
            acc.y = fmaf(fv.x, w0.y, acc.y);
            acc.z = fmaf(fv.x, w0.z, acc.z);
            acc.w = fmaf(fv.x, w0.w, acc.w);
            acc.x = fmaf(fv.y, w1.x, acc.x);
            acc.y = fmaf(fv.y, w1.y, acc.y);
            acc.z = fmaf(fv.y, w1.z, acc.z);
            acc.w = fmaf(fv.y, w1.w, acc.w);
            acc.x = fmaf(fv.z, w2.x, acc.x);
            acc.y = fmaf(fv.z, w2.y, acc.y);
            acc.z = fmaf(fv.z, w2.z, acc.z);
            acc.w = fmaf(fv.z, w2.w, acc.w);
            acc.x = fmaf(fv.w, w3.x, acc.x);
            acc.y = fmaf(fv.w, w3.y, acc.y);
            acc.z = fmaf(fv.w, w3.z, acc.z);
            acc.w = fmaf(fv.w, w3.w, acc.w);
        }
        red[w][l] = acc;               // 16B/lane contiguous -> conflict-free
        __syncthreads();               // partials ready

        if (t < NC / 4) {              // wave 0 reduces + stores
            const float4 s0 = red[0][t];
            const float4 s1 = red[1][t];
            const float4 s2 = red[2][t];
            const float4 s3 = red[3][t];
            const float4 bv = *reinterpret_cast<const float4*>(&bias[deg * NC + t * 4]);
            float4 o;
            o.x = fmaxf(s0.x + s1.x + s2.x + s3.x + bv.x, 0.f);
            o.y = fmaxf(s0.y + s1.y + s2.y + s3.y + bv.y, 0.f);
            o.z = fmaxf(s0.z + s1.z + s2.z + s3.z + bv.z, 0.f);
            o.w = fmaxf(s0.w + s1.w + s2.w + s3.w + bv.w, 0.f);
            *reinterpret_cast<float4*>(&out[(size_t)row * NC + t * 4]) = o;
        }
        __syncthreads();               // feat/red reusable for next row
    }
}

// ---------------------------------------------------------------------------
extern "C" void kernel_launch(void* const* d_in, const int* in_sizes, int n_in,
                              void* d_out, int out_size, void* d_ws, size_t ws_size,
                              hipStream_t stream) {
    const float* atoms = (const float*)d_in[0];
    const float* bonds = (const float*)d_in[1];
    const int*   edges = (const int*)  d_in[2];
    const float* W     = (const float*)d_in[3];
    const float* bias  = (const float*)d_in[4];
    float*       out   = (float*)d_out;

    // Bulk zero-fill via the runtime's tuned fill path (~6.5 TB/s on this
    // chip vs ~0.8 TB/s for our in-kernel scattered zero stores).
    // d_ws deliberately untouched (ws use costs a 256MiB re-poison fill).
    hipMemsetAsync(out, 0, (size_t)NROWS * NC * sizeof(float), stream);

    ngh_needy<<<dim3(NBLK), dim3(256), 0, stream>>>(
        atoms, bonds, edges, W, bias, out);
}

// Round 7
// 134.752 us; speedup vs baseline: 1.0284x; 1.0284x over previous
//
#include <hip/hip_runtime.h>

// B=256, A=128, D=5, FA=256, FB=64, C=256, F=320.
// deg==5 (~96.2% rows) -> zero row. ~1250 needy rows need feat(320)@W[deg](320x256).
//
// Ledger:
//   R1: touching d_ws => extra 256MiB re-poison fill. Never use workspace.
//       Fixed floor = 2 fills ~82us + ours.
//   R2: 512 blocks + serial 8-row chunks + scalar W loads = 69us.
//   R5: 4096 blocks, float4 W loads = 42.5us  (== R0's 43.7us).
//   R6: same minus all zero stores (memset instead) => still ~40us.
//   => Invariant cost identified: W panel BYTES. Every version reads 320KB
//      per needy row: 1250 x 320KB = 400MB of hot-set L2 traffic ~ 10TB/s
//      ceiling ~ 40us. Round-trip-count changes never touched the bytes.
//
// This version: 256 blocks x 512 threads x 128 rows. Per-deg LDS compaction,
// batches of G=8 rows share ONE panel read => ~89MB panel traffic (4.5x cut).
// Zero stores (trivial rows only, needy skipped) overlap compute, no 2nd op.

#define NB 256
#define NA 128
#define ND 5
#define NFA 256
#define NFB 64
#define NC 256
#define NF (NFA + NFB)      // 320
#define NROWS (NB * NA)     // 32768
#define RPB 128             // rows per block
#define NBLK (NROWS / RPB)  // 256 blocks -> 1/CU
#define NT 512              // threads -> 8 waves
#define G 8                 // rows per panel pass
#define FPW (NF / 8)        // 40 f-rows per wave

__device__ __forceinline__ float4 fma4(float s, float4 wv, float4 a) {
    a.x = fmaf(s, wv.x, a.x);
    a.y = fmaf(s, wv.y, a.y);
    a.z = fmaf(s, wv.z, a.z);
    a.w = fmaf(s, wv.w, a.w);
    return a;
}

__global__ __launch_bounds__(NT) void ngh_kernel(
    const float* __restrict__ atoms,   // B*A*FA
    const float* __restrict__ bonds,   // B*A*D*FB
    const int*   __restrict__ edges,   // B*A*D
    const float* __restrict__ W,       // D*F*C
    const float* __restrict__ bias,    // D*C
    float* __restrict__ out)           // B*A*C
{
    __shared__ int eds[RPB * ND];                 // 2.5 KB
    __shared__ int cnt_s[ND];
    __shared__ int lists[ND][RPB];                // 2.5 KB
    __shared__ unsigned mask[4];                  // needy bitmask, 128 bits
    __shared__ int rows_s[G];
    __shared__ alignas(16) float  feat[NF * G];   // [f][r], 10 KB
    __shared__ alignas(16) float4 red[8][G][64];  // 64 KB (per-wave partials)

    const int t  = threadIdx.x;
    const int r0 = blockIdx.x * RPB;
    const int w  = t >> 6;              // wave 0..7
    const int l  = t & 63;              // lane

    if (t < ND) cnt_s[t] = 0;
    if (t < 4)  mask[t]  = 0u;

    // Stage 640 edge ints, coalesced (512 + 128).
    eds[t] = edges[r0 * ND + t];
    if (t < RPB * ND - NT) eds[NT + t] = edges[r0 * ND + NT + t];
    __syncthreads();

    // Degree scan -> per-deg lists (LOCAL row idx) + needy bitmask.
    if (t < RPB) {
        int dg = 0;
#pragma unroll
        for (int d = 0; d < ND; ++d) dg += (eds[t * ND + d] != -1) ? 1 : 0;
        if (dg < ND) {
            const int p = atomicAdd(&cnt_s[dg], 1);
            lists[dg][p] = t;
            atomicOr(&mask[t >> 5], 1u << (t & 31));
        }
    }
    __syncthreads();

    // Zero trivial rows (needy rows skipped -> no store-store ordering issue).
    // No barrier after: these stores drain under the compute below.
    {
        float4* o4 = reinterpret_cast<float4*>(out + (size_t)r0 * NC);
        const float4 z = make_float4(0.f, 0.f, 0.f, 0.f);
#pragma unroll
        for (int k = 0; k < (RPB * NC / 4) / NT; ++k) {   // 16 iters
            const int i  = t + k * NT;
            const int lr = i >> 6;                        // local row of item
            if (!((mask[lr >> 5] >> (lr & 31)) & 1u)) o4[i] = z;
        }
    }

    // Needy batches: all loop bounds/branches below are block-uniform
    // (LDS broadcast reads); barriers never sit behind divergent control.
    for (int d = 0; d < ND; ++d) {
        const int n = cnt_s[d];
        for (int j0 = 0; j0 < n; j0 += G) {
            const int nr = min(G, n - j0);
            if (t < G) rows_s[t] = (t < nr) ? lists[d][j0 + t] : -1;
            __syncthreads();

            // Build feat[f][r]: t<256 atom channels, t in [256,320) bonds.
            if (t < NFA) {
#pragma unroll
                for (int r = 0; r < G; ++r) {
                    const int lrow = rows_s[r];
                    float v = 0.f;
                    if (lrow >= 0) {
                        const int row = r0 + lrow;
                        const int rb  = row & ~(NA - 1);   // b*NA
                        v = atoms[(size_t)row * NFA + t];
#pragma unroll
                        for (int dd = 0; dd < ND; ++dd) {
                            const int e = eds[lrow * ND + dd];
                            if (e != -1) v += atoms[(size_t)(rb + e) * NFA + t];
                        }
                    }
                    feat[t * G + r] = v;
                }
            } else if (t < NFA + NFB) {
                const int f = t - NFA;
#pragma unroll
                for (int r = 0; r < G; ++r) {
                    const int lrow = rows_s[r];
                    float v = 0.f;
                    if (lrow >= 0) {
                        const float* br = bonds + (size_t)(r0 + lrow) * (ND * NFB) + f;
#pragma unroll
                        for (int dd = 0; dd < ND; ++dd) v += br[dd * NFB];
                    }
                    feat[(NFA + f) * G + r] = v;
                }
            }
            __syncthreads();

            // Matvec: wave w owns f in [40w, 40w+40); lane owns 4 channels.
            // Per f: ONE float4 W load (1KB/wave, coalesced) feeds 32 FMAs.
            float4 acc[G];
#pragma unroll
            for (int r = 0; r < G; ++r) acc[r] = make_float4(0.f, 0.f, 0.f, 0.f);
            {
                const float4* f4 = reinterpret_cast<const float4*>(feat);
                const float*  Wd = W + (size_t)d * (NF * NC);
                const int fbase = w * FPW;
#pragma unroll 4
                for (int fi = 0; fi < FPW; ++fi) {
                    const int f = fbase + fi;
                    const float4 wv = *reinterpret_cast<const float4*>(
                        &Wd[(size_t)f * NC + l * 4]);
                    const float4 p0 = f4[f * 2];       // feat[f][0..3] bcast
                    const float4 p1 = f4[f * 2 + 1];   // feat[f][4..7] bcast
                    acc[0] = fma4(p0.x, wv, acc[0]);
                    acc[1] = fma4(p0.y, wv, acc[1]);
                    acc[2] = fma4(p0.z, wv, acc[2]);
                    acc[3] = fma4(p0.w, wv, acc[3]);
                    acc[4] = fma4(p1.x, wv, acc[4]);
                    acc[5] = fma4(p1.y, wv, acc[5]);
                    acc[6] = fma4(p1.z, wv, acc[6]);
                    acc[7] = fma4(p1.w, wv, acc[7]);
                }
            }
#pragma unroll
            for (int r = 0; r < G; ++r) red[w][r][l] = acc[r];   // b128, conflict-free
            __syncthreads();

            // Cross-wave reduce + bias + relu + store: 512 threads = 8 rows x 64 lanes.
            {
                const int r    = t >> 6;
                const int li   = t & 63;
                const int lrow = rows_s[r];
                if (lrow >= 0) {
                    float4 s = red[0][r][li];
#pragma unroll
                    for (int wi = 1; wi < 8; ++wi) {
                        const float4 q = red[wi][r][li];
                        s.x += q.x; s.y += q.y; s.z += q.z; s.w += q.w;
                    }
                    const float4 bv = *reinterpret_cast<const float4*>(
                        &bias[d * NC + li * 4]);
                    float4 o;
                    o.x = fmaxf(s.x + bv.x, 0.f);
                    o.y = fmaxf(s.y + bv.y, 0.f);
                    o.z = fmaxf(s.z + bv.z, 0.f);
                    o.w = fmaxf(s.w + bv.w, 0.f);
                    *reinterpret_cast<float4*>(
                        &out[(size_t)(r0 + lrow) * NC + li * 4]) = o;
                }
            }
            __syncthreads();   // rows_s/feat/red reusable for next batch
        }
    }
}

// ---------------------------------------------------------------------------
extern "C" void kernel_launch(void* const* d_in, const int* in_sizes, int n_in,
                              void* d_out, int out_size, void* d_ws, size_t ws_size,
                              hipStream_t stream) {
    const float* atoms = (const float*)d_in[0];
    const float* bonds = (const float*)d_in[1];
    const int*   edges = (const int*)  d_in[2];
    const float* W     = (const float*)d_in[3];
    const float* bias  = (const float*)d_in[4];
    float*       out   = (float*)d_out;

    // Single dispatch; d_ws deliberately untouched (re-poison tax).
    ngh_kernel<<<dim3(NBLK), dim3(NT), 0, stream>>>(
        atoms, bonds, edges, W, bias, out);
}